// Round 1
// baseline (77.628 us; speedup 1.0000x reference)
//
#include <hip/hip_runtime.h>

// 5-qubit state: index = a*16 + b*8 + c*4 + d*2 + e
// wire0=a=bit4, wire1=b=bit3, wire2=c=bit2, wire3=d=bit1, wire4=e=bit0

template<int BIT>
__device__ __forceinline__ void apply_rx(float (&sr)[32], float (&si)[32],
                                         float c, float s) {
    // gate [[c, -i*s], [-i*s, c]], s = sin(ang/2), c = cos(ang/2)
#pragma unroll
    for (int m = 0; m < 16; ++m) {
        const int lo = m & ((1 << BIT) - 1);
        const int hi = (m >> BIT) << (BIT + 1);
        const int i0 = hi | lo;
        const int i1 = i0 | (1 << BIT);
        const float ar = sr[i0], ai = si[i0];
        const float br = sr[i1], bi = si[i1];
        // new0 = c*a - i*s*b
        sr[i0] = c * ar + s * bi;
        si[i0] = c * ai - s * br;
        // new1 = -i*s*a + c*b
        sr[i1] = s * ai + c * br;
        si[i1] = c * bi - s * ar;
    }
}

template<int CBIT, int TBIT>
__device__ __forceinline__ void apply_cu(float (&sr)[32], float (&si)[32],
                                         float u01r, float u01i,
                                         float u10r, float u10i) {
    // for control bit == 1: (t0, t1) -> (u01 * t1, u10 * t0)
#pragma unroll
    for (int m = 0; m < 16; ++m) {
        const int lo = m & ((1 << TBIT) - 1);
        const int hi = (m >> TBIT) << (TBIT + 1);
        const int i0 = hi | lo;
        if (!(i0 & (1 << CBIT))) continue;   // compile-time eliminated
        const int i1 = i0 | (1 << TBIT);
        const float ar = sr[i0], ai = si[i0];
        const float br = sr[i1], bi = si[i1];
        sr[i0] = u01r * br - u01i * bi;
        si[i0] = u01r * bi + u01i * br;
        sr[i1] = u10r * ar - u10i * ai;
        si[i1] = u10r * ai + u10i * ar;
    }
}

__global__ __launch_bounds__(256)
void qsim_kernel(const float* __restrict__ x,
                 const float* __restrict__ thetas,
                 const float* __restrict__ phis,
                 float* __restrict__ out, int P) {
    const int p = blockIdx.x * blockDim.x + threadIdx.x;
    if (p >= P) return;

    // p = ((b*128 + i)*128 + j)
    const int b   = p >> 14;
    const int rem = p & 16383;
    const int i   = rem >> 7;
    const int j   = rem & 127;

    // load 12 patch pixels: pix[4*c + 2*dy + dx] = x[b, c, 2i+dy, 2j+dx]
    float pix[12];
    const float2* __restrict__ x2 = (const float2*)x;
#pragma unroll
    for (int c = 0; c < 3; ++c) {
#pragma unroll
        for (int dy = 0; dy < 2; ++dy) {
            const long row = ((long)(b * 3 + c) * 256 + (2 * i + dy));
            const float2 v = x2[row * 128 + j];
            pix[c * 4 + dy * 2 + 0] = v.x;
            pix[c * 4 + dy * 2 + 1] = v.y;
        }
    }

    // state after initial H on wire0: (|00000> + |10000>)/sqrt(2)
    float sr[32], si[32];
#pragma unroll
    for (int m = 0; m < 32; ++m) { sr[m] = 0.f; si[m] = 0.f; }
    sr[0]  = 0.70710678118654752f;
    sr[16] = 0.70710678118654752f;

#pragma unroll
    for (int L = 0; L < 3; ++L) {
        // RX on wires 1..4 (bits 3..0) with pixel angles
        {
            float sn, cs;
            __sincosf(0.5f * pix[4 * L + 0], &sn, &cs); apply_rx<3>(sr, si, cs, sn);
            __sincosf(0.5f * pix[4 * L + 1], &sn, &cs); apply_rx<2>(sr, si, cs, sn);
            __sincosf(0.5f * pix[4 * L + 2], &sn, &cs); apply_rx<1>(sr, si, cs, sn);
            __sincosf(0.5f * pix[4 * L + 3], &sn, &cs); apply_rx<0>(sr, si, cs, sn);
        }
        // controlled-X_theta gates: (ctrl,tgt) bit pairs (3,2),(2,1),(1,0),(0,3)
        // u01 = -i e^{+i t/2} = sin - i cos ; u10 = -i e^{-i t/2} = -sin - i cos
        {
            float sn, cs;
            __sincosf(0.5f * thetas[4 * L + 0], &sn, &cs);
            apply_cu<3, 2>(sr, si, sn, -cs, -sn, -cs);
            __sincosf(0.5f * thetas[4 * L + 1], &sn, &cs);
            apply_cu<2, 1>(sr, si, sn, -cs, -sn, -cs);
            __sincosf(0.5f * thetas[4 * L + 2], &sn, &cs);
            apply_cu<1, 0>(sr, si, sn, -cs, -sn, -cs);
            __sincosf(0.5f * thetas[4 * L + 3], &sn, &cs);
            apply_cu<0, 3>(sr, si, sn, -cs, -sn, -cs);
        }
        // CPhase(phi) on wires 0,1 -> amplitudes with bit4 & bit3 set (24..31)
        {
            float sn, cs;
            __sincosf(phis[L], &sn, &cs);
#pragma unroll
            for (int m = 24; m < 32; ++m) {
                const float ar = sr[m], ai = si[m];
                sr[m] = cs * ar - sn * ai;
                si[m] = cs * ai + sn * ar;
            }
        }
    }

    // final H on wire0 + <Z0> folds to: ev = sum over lower-bit pairs of
    // 2*Re(v0 * conj(v1)), v0 = bit4-clear, v1 = bit4-set
    float ev = 0.f;
#pragma unroll
    for (int m = 0; m < 16; ++m) {
        ev += sr[m] * sr[m + 16] + si[m] * si[m + 16];
    }
    out[p] = 2.f * ev;
}

extern "C" void kernel_launch(void* const* d_in, const int* in_sizes, int n_in,
                              void* d_out, int out_size, void* d_ws, size_t ws_size,
                              hipStream_t stream) {
    const float* x      = (const float*)d_in[0];
    const float* thetas = (const float*)d_in[1];
    const float* phis   = (const float*)d_in[2];
    float* out = (float*)d_out;
    const int P = out_size;               // 16 * 128 * 128 = 262144
    const int threads = 256;
    const int blocks = (P + threads - 1) / threads;
    qsim_kernel<<<blocks, threads, 0, stream>>>(x, thetas, phis, out, P);
}

// Round 2
// 77.627 us; speedup vs baseline: 1.0000x; 1.0000x over previous
//
#include <hip/hip_runtime.h>

// 5-qubit state: index = a*16 + b*8 + c*4 + d*2 + e
// wire0=a=bit4, wire1=b=bit3, wire2=c=bit2, wire3=d=bit1, wire4=e=bit0

// sin/cos of ang/2 via native v_sin/v_cos (input in revolutions).
// |ang| <~ 6 for N(0,1) inputs -> |rev| < 0.5, well inside HW range.
__device__ __forceinline__ void sc_half(float ang, float& s, float& c) {
    const float r = ang * 0.07957747154594767f;   // (ang/2) / (2*pi)
    s = __builtin_amdgcn_sinf(r);
    c = __builtin_amdgcn_cosf(r);
}
__device__ __forceinline__ void sc_full(float ang, float& s, float& c) {
    const float r = ang * 0.15915494309189535f;   // ang / (2*pi)
    s = __builtin_amdgcn_sinf(r);
    c = __builtin_amdgcn_cosf(r);
}

template<int BIT>
__device__ __forceinline__ void apply_rx(float (&sr)[32], float (&si)[32],
                                         float c, float s) {
    // gate [[c, -i*s], [-i*s, c]]
#pragma unroll
    for (int m = 0; m < 16; ++m) {
        const int lo = m & ((1 << BIT) - 1);
        const int hi = (m >> BIT) << (BIT + 1);
        const int i0 = hi | lo;
        const int i1 = i0 | (1 << BIT);
        const float ar = sr[i0], ai = si[i0];
        const float br = sr[i1], bi = si[i1];
        sr[i0] = c * ar + s * bi;
        si[i0] = c * ai - s * br;
        sr[i1] = s * ai + c * br;
        si[i1] = c * bi - s * ar;
    }
}

template<int CBIT, int TBIT>
__device__ __forceinline__ void apply_cu(float (&sr)[32], float (&si)[32],
                                         float u01r, float u01i,
                                         float u10r, float u10i) {
    // control bit == 1: (t0, t1) -> (u01 * t1, u10 * t0)
#pragma unroll
    for (int m = 0; m < 16; ++m) {
        const int lo = m & ((1 << TBIT) - 1);
        const int hi = (m >> TBIT) << (TBIT + 1);
        const int i0 = hi | lo;
        if (!(i0 & (1 << CBIT))) continue;   // compile-time eliminated
        const int i1 = i0 | (1 << TBIT);
        const float ar = sr[i0], ai = si[i0];
        const float br = sr[i1], bi = si[i1];
        sr[i0] = u01r * br - u01i * bi;
        si[i0] = u01r * bi + u01i * br;
        sr[i1] = u10r * ar - u10i * ai;
        si[i1] = u10r * ai + u10i * ar;
    }
}

__global__ __launch_bounds__(256)
void qsim_kernel(const float* __restrict__ x,
                 const float* __restrict__ thetas,
                 const float* __restrict__ phis,
                 float* __restrict__ out, int P) {
    const int p = blockIdx.x * blockDim.x + threadIdx.x;
    if (p >= P) return;

    const int b   = p >> 14;
    const int rem = p & 16383;
    const int i   = rem >> 7;
    const int j   = rem & 127;

    // 12 patch pixels: pix[4*c + 2*dy + dx] = x[b, c, 2i+dy, 2j+dx]
    float pix[12];
    const float2* __restrict__ x2 = (const float2*)x;
#pragma unroll
    for (int c = 0; c < 3; ++c) {
#pragma unroll
        for (int dy = 0; dy < 2; ++dy) {
            const long row = ((long)(b * 3 + c) * 256 + (2 * i + dy));
            const float2 v = x2[row * 128 + j];
            pix[c * 4 + dy * 2 + 0] = v.x;
            pix[c * 4 + dy * 2 + 1] = v.y;
        }
    }

    // ---- fold H(wire0) + layer-1 RX into product-state init ----
    // amp(a, bcde) = prod_w [cos(x_w/2) if bit==0 else -i*sin(x_w/2)]
    //              = m(bcde) * (-i)^popcount(bcde), identical for a=0,1.
    // (global 1/sqrt2 dropped; cancels the final factor-2 in <Z0>.)
    float sr[32], si[32];
    {
        float s1, c1, s2, c2, s3, c3, s4, c4;
        sc_half(pix[0], s1, c1);
        sc_half(pix[1], s2, c2);
        sc_half(pix[2], s3, c3);
        sc_half(pix[3], s4, c4);
        const float pA[4] = {c1 * c2, c1 * s2, s1 * c2, s1 * s2}; // bits 3,2
        const float pB[4] = {c3 * c4, c3 * s4, s3 * c4, s3 * s4}; // bits 1,0
#pragma unroll
        for (int m = 0; m < 16; ++m) {
            const float v = pA[m >> 2] * pB[m & 3];
            const int pc = __builtin_popcount((unsigned)m) & 3;
            sr[m] = (pc == 0) ? v : ((pc == 2) ? -v : 0.f);
            si[m] = (pc == 1) ? -v : ((pc == 3) ? v : 0.f);
        }
#pragma unroll
        for (int m = 0; m < 16; ++m) { sr[m + 16] = sr[m]; si[m + 16] = si[m]; }
    }

#pragma unroll
    for (int L = 0; L < 3; ++L) {
        // RX on wires 1..4 (skip for L==0: folded into init)
        if (L > 0) {
            float sn, cs;
            sc_half(pix[4 * L + 0], sn, cs); apply_rx<3>(sr, si, cs, sn);
            sc_half(pix[4 * L + 1], sn, cs); apply_rx<2>(sr, si, cs, sn);
            sc_half(pix[4 * L + 2], sn, cs); apply_rx<1>(sr, si, cs, sn);
            sc_half(pix[4 * L + 3], sn, cs); apply_rx<0>(sr, si, cs, sn);
        }
        // controlled-X_theta: (ctrl,tgt) bits (3,2),(2,1),(1,0),(0,3)
        // u01 = sin - i*cos ; u10 = -sin - i*cos  (of theta/2)
        {
            float sn, cs;
            sc_half(thetas[4 * L + 0], sn, cs);
            apply_cu<3, 2>(sr, si, sn, -cs, -sn, -cs);
            sc_half(thetas[4 * L + 1], sn, cs);
            apply_cu<2, 1>(sr, si, sn, -cs, -sn, -cs);
            sc_half(thetas[4 * L + 2], sn, cs);
            apply_cu<1, 0>(sr, si, sn, -cs, -sn, -cs);
            sc_half(thetas[4 * L + 3], sn, cs);
            apply_cu<0, 3>(sr, si, sn, -cs, -sn, -cs);
        }
        // CPhase(phi) on wires 0,1 -> amps 24..31
        {
            float sn, cs;
            sc_full(phis[L], sn, cs);
#pragma unroll
            for (int m = 24; m < 32; ++m) {
                const float ar = sr[m], ai = si[m];
                sr[m] = cs * ar - sn * ai;
                si[m] = cs * ai + sn * ar;
            }
        }
    }

    // final H on wire0 + <Z0>:  ev = sum_m Re(v_m * conj(v_{m+16}))
    // (factor 2 cancelled by dropped 1/sqrt2 init scale)
    float ev = 0.f;
#pragma unroll
    for (int m = 0; m < 16; ++m) {
        ev += sr[m] * sr[m + 16] + si[m] * si[m + 16];
    }
    out[p] = ev;
}

extern "C" void kernel_launch(void* const* d_in, const int* in_sizes, int n_in,
                              void* d_out, int out_size, void* d_ws, size_t ws_size,
                              hipStream_t stream) {
    const float* x      = (const float*)d_in[0];
    const float* thetas = (const float*)d_in[1];
    const float* phis   = (const float*)d_in[2];
    float* out = (float*)d_out;
    const int P = out_size;               // 16 * 128 * 128 = 262144
    const int threads = 256;
    const int blocks = (P + threads - 1) / threads;
    qsim_kernel<<<blocks, threads, 0, stream>>>(x, thetas, phis, out, P);
}